// Round 18
// baseline (2814.076 us; speedup 1.0000x reference)
//
#include <hip/hip_runtime.h>
#include <stdint.h>

#define NB 8
#define NN 8192
#define NP 2048
#define NSAMP 32
#define NC 64
#define STRIDE 34   // words/lane segment: 136B (b64-aligned), bank=2l -> 2-way (free)

typedef float v2f __attribute__((ext_vector_type(2)));

// ---------------------------------------------------------------------------
// prep: weight transposes for coalesced per-k reads in the fused MLP kernel.
// ---------------------------------------------------------------------------
__global__ __launch_bounds__(256) void prep_kernel(
    const float* __restrict__ w1, const float* __restrict__ w2,
    const float* __restrict__ w3, float* __restrict__ w1t,
    float* __restrict__ w2t, float* __restrict__ w3t)
{
    int j = blockIdx.x * 256 + threadIdx.x;
    if (j < 64*67) { int o = j / 67, k = j % 67; w1t[k*64 + o] = w1[j]; }
    int j2 = j - 64*67;
    if (j2 >= 0 && j2 < 64*64) { int o = j2 >> 6, k = j2 & 63; w2t[k*64 + o] = w2[j2]; }
    int j3 = j2 - 64*64;
    if (j3 >= 0 && j3 < 128*64) { int o = j3 >> 6, k = j3 & 63; w3t[k*128 + o] = w3[j3]; }
}

// ---------------------------------------------------------------------------
// FPS v11 = r17 champion (1705us, absmax 0.0) with ONE structural change:
// immutable point coords move from registers (96 VGPRs) to LDS SoA; only the
// mutable D array (32 VGPRs) stays resident. Theory: r17's VGPR_Count=132 with
// 128 array regs leaves ~4 free -> accvgpr shuffling + serialized chains
// (~680 issued inst/iter vs ~290 source slots). Freeing ~90 regs restores ILP.
// Everything else byte-identical semantics to r17:
//   - 256 threads, 32 pts/lane (lane t owns global points t*32..t*32+31)
//   - packed v2f distance update, separate-op f32, contract(off):
//       d = ((dx*dx + dy*dy) + dz*dz); dist = min(dist, d)
//   - 4 integrated strict-> chains over ascending 8-pt sub-ranges
//   - DPP wave max; ballot+ctz+readlane first-occurrence (r17-verified)
//   - parity-dbuf 4-slot merge, ONE barrier/iter, t0 global writes
// ---------------------------------------------------------------------------
#define DPP_MAXF(m, CTRL) do { \
    int _s = __builtin_amdgcn_update_dpp(__float_as_int(m), __float_as_int(m), \
                                         CTRL, 0xf, 0xf, false); \
    float _f = __int_as_float(_s); \
    m = fmaxf(m, _f); } while (0)

__global__ __launch_bounds__(256) void fps_kernel(
    const float* __restrict__ xyz, int* __restrict__ fps_idx,
    float* __restrict__ out_newxyz)
{
#pragma clang fp contract(off)
    __shared__ float cx[256 * STRIDE];   // 34816 B
    __shared__ float cy[256 * STRIDE];
    __shared__ float cz[256 * STRIDE];   // 3x = 104448 B
    __shared__ float bv[2][4];
    __shared__ int   bix[2][4];

    const int b = blockIdx.x;
    const int t = threadIdx.x;
    const int lane = t & 63;
    const int w = t >> 6;
    const float* base = xyz + (size_t)b * NN * 3;

    // stage: coalesced float4 global reads, scatter to per-lane SoA segments.
    // word u of the (N,3) array: point u/3, coord u%3; point p lives at
    // segment slot (p>>5)*STRIDE + (p&31)  (lane p>>5 owns it).
    for (int q = t; q < NN * 3 / 4; q += 256) {
        float4 v = ((const float4*)base)[q];
        int u0 = q * 4;
        #pragma unroll
        for (int e = 0; e < 4; e++) {
            int u = u0 + e;
            int pt = u / 3, c = u - pt * 3;
            int slot = (pt >> 5) * STRIDE + (pt & 31);
            float val = (e == 0) ? v.x : (e == 1) ? v.y : (e == 2) ? v.z : v.w;
            if (c == 0) cx[slot] = val;
            else if (c == 1) cy[slot] = val;
            else cz[slot] = val;
        }
    }
    __syncthreads();

    // mutable per-point running min distance (only resident array)
    v2f D[16];
    #pragma unroll
    for (int j = 0; j < 16; j++) D[j] = (v2f){ 1e10f, 1e10f };

    const int p0 = t * 32;
    const v2f* xp = (const v2f*)&cx[t * STRIDE];   // 8B-aligned (136B stride)
    const v2f* yp = (const v2f*)&cy[t * STRIDE];
    const v2f* zp = (const v2f*)&cz[t * STRIDE];

    int far = 0;
    for (int k = 0; k < NP; k++) {
        int fslot = (far >> 5) * STRIDE + (far & 31);
        float fx = cx[fslot];            // broadcast reads (same addr all lanes)
        float fy = cy[fslot];
        float fz = cz[fslot];
        if (t == 0) {
            fps_idx[b * NP + k] = far;
            out_newxyz[((size_t)b * NP + k) * 3 + 0] = fx;
            out_newxyz[((size_t)b * NP + k) * 3 + 1] = fy;
            out_newxyz[((size_t)b * NP + k) * 3 + 2] = fz;
        }

        v2f fx2 = { fx, fx }, fy2 = { fy, fy }, fz2 = { fz, fz };

        // 4 independent (best,idx) chains over ascending 8-point sub-ranges;
        // packed distance update, scalar strict-> bookkeeping (r17 form)
        float bv0 = -1.f, bv1 = -1.f, bv2 = -1.f, bv3 = -1.f;
        int   bi0 = 0,    bi1 = 0,    bi2 = 0,    bi3 = 0;
        #pragma unroll
        for (int p = 0; p < 4; p++) {
            v2f dx = xp[p] - fx2, dy = yp[p] - fy2, dz = zp[p] - fz2;
            v2f d  = (dx*dx + dy*dy) + dz*dz;    // contract(off): 5 rounded ops
            v2f nd = __builtin_elementwise_min(D[p], d);
            D[p] = nd;
            if (nd.x > bv0) { bv0 = nd.x; bi0 = p0 + 2*p; }
            if (nd.y > bv0) { bv0 = nd.y; bi0 = p0 + 2*p + 1; }
        }
        #pragma unroll
        for (int p = 4; p < 8; p++) {
            v2f dx = xp[p] - fx2, dy = yp[p] - fy2, dz = zp[p] - fz2;
            v2f d  = (dx*dx + dy*dy) + dz*dz;
            v2f nd = __builtin_elementwise_min(D[p], d);
            D[p] = nd;
            if (nd.x > bv1) { bv1 = nd.x; bi1 = p0 + 2*p; }
            if (nd.y > bv1) { bv1 = nd.y; bi1 = p0 + 2*p + 1; }
        }
        #pragma unroll
        for (int p = 8; p < 12; p++) {
            v2f dx = xp[p] - fx2, dy = yp[p] - fy2, dz = zp[p] - fz2;
            v2f d  = (dx*dx + dy*dy) + dz*dz;
            v2f nd = __builtin_elementwise_min(D[p], d);
            D[p] = nd;
            if (nd.x > bv2) { bv2 = nd.x; bi2 = p0 + 2*p; }
            if (nd.y > bv2) { bv2 = nd.y; bi2 = p0 + 2*p + 1; }
        }
        #pragma unroll
        for (int p = 12; p < 16; p++) {
            v2f dx = xp[p] - fx2, dy = yp[p] - fy2, dz = zp[p] - fz2;
            v2f d  = (dx*dx + dy*dy) + dz*dz;
            v2f nd = __builtin_elementwise_min(D[p], d);
            D[p] = nd;
            if (nd.x > bv3) { bv3 = nd.x; bi3 = p0 + 2*p; }
            if (nd.y > bv3) { bv3 = nd.y; bi3 = p0 + 2*p + 1; }
        }
        // merge chains (ranges ascend; strict > keeps earliest on tie)
        float best = bv0; int bj = bi0;
        if (bv1 > best) { best = bv1; bj = bi1; }
        if (bv2 > best) { best = bv2; bj = bi2; }
        if (bv3 > best) { best = bv3; bj = bi3; }

        // wave max via DPP (row_shr 1,2,4,8 then row_bcast 15,31 -> lane 63)
        float m = best;
        DPP_MAXF(m, 0x111); DPP_MAXF(m, 0x112); DPP_MAXF(m, 0x114);
        DPP_MAXF(m, 0x118); DPP_MAXF(m, 0x142); DPP_MAXF(m, 0x143);
        float wm = __int_as_float(__builtin_amdgcn_readlane(__float_as_int(m), 63));

        // first-occurrence: lowest lane whose best == wm (lane ranges ascend;
        // its bj is its own first occurrence) — verified r12/r15/r16/r17
        unsigned long long mk = __ballot(best == wm);
        int L = (int)__builtin_ctzll(mk);
        int widx = __builtin_amdgcn_readlane(bj, L);

        if (lane == 0) { bv[k & 1][w] = wm; bix[k & 1][w] = widx; }
        __syncthreads();

        // redundant 4-way merge on every wave (wave ranges ascend; strict >)
        float v0 = bv[k & 1][0], v1 = bv[k & 1][1];
        float v2 = bv[k & 1][2], v3 = bv[k & 1][3];
        int   i0 = bix[k & 1][0], i1 = bix[k & 1][1];
        int   i2 = bix[k & 1][2], i3 = bix[k & 1][3];
        float gv = v0; int gi = i0;
        if (v1 > gv) { gv = v1; gi = i1; }
        if (v2 > gv) { gv = v2; gi = i2; }
        if (v3 > gv) { gv = v3; gi = i3; }
        far = gi;
    }
}

// ---------------------------------------------------------------------------
// Fused ball-query + group + 3-layer MLP + max-pool. One wave per query.
// VERIFIED rounds 7-17 (absmax 0.0). d2: pp/qq separate-op, dot FMA chain,
// d2 separate-op, strict < 0.04f. DO NOT TOUCH.
// ---------------------------------------------------------------------------
__global__ __launch_bounds__(64) void fused_kernel(
    const float* __restrict__ xyz, const float* __restrict__ features,
    const int* __restrict__ fps_idx,
    const float* __restrict__ w1t, const float* __restrict__ b1,
    const float* __restrict__ w2t, const float* __restrict__ b2,
    const float* __restrict__ w3t, const float* __restrict__ b3,
    float* __restrict__ out_feat)
{
#pragma clang fp contract(off)
    constexpr int XP = 36;
    __shared__ __align__(16) float Xs[67 * XP];
    __shared__ __align__(16) float Hs[64 * XP];
    __shared__ int ids[NSAMP];

    const int q = blockIdx.x;           // b*NP + s
    const int b = q >> 11, s = q & (NP - 1);
    const int lane = threadIdx.x;
    const float* base = xyz + (size_t)b * NN * 3;

    // ---- ball query (one wave) ----
    int qi = fps_idx[q];
    float qx = base[qi*3+0], qy = base[qi*3+1], qz = base[qi*3+2];
    float qq = (qx*qx + qy*qy) + qz*qz;              // separate-op (contract off)
    const float RR = 0.04f;                          // f32(0.2*0.2), strict <

    int have = 0, first = 0;
    for (int c = 0; c < NN / 64; c++) {
        int p = c * 64 + lane;
        float px = base[p*3+0], py = base[p*3+1], pz = base[p*3+2];
        float pp  = (px*px + py*py) + pz*pz;         // separate-op
        float dot = fmaf(qz, pz, fmaf(qy, py, qx*px));  // einsum FMA chain
        float d2  = (qq + pp) - 2.0f*dot;            // separate-op
        bool pred = d2 < RR;
        unsigned long long m = __ballot(pred);
        if (have == 0 && m) first = c * 64 + (int)__builtin_ctzll(m);
        if (pred) {
            int rank = have + (int)__popcll(m & ((1ULL << lane) - 1ULL));
            if (rank < NSAMP) ids[rank] = p;
        }
        have += (int)__popcll(m);
        if (have >= NSAMP) break;
    }
    if (lane < NSAMP && lane >= have) ids[lane] = first;
    __syncthreads();

    // ---- build X: rows 0..2 = grouped_xyz - center, rows 3..66 = features ----
    if (lane < NSAMP) {
        int id = ids[lane];
        Xs[0*XP + lane] = base[id*3+0] - qx;
        Xs[1*XP + lane] = base[id*3+1] - qy;
        Xs[2*XP + lane] = base[id*3+2] - qz;
    }
    {
        const float* frow = features + ((size_t)b * NC + lane) * NN;
        #pragma unroll
        for (int n0 = 0; n0 < NSAMP; n0 += 4) {
            float4 v;
            v.x = frow[ids[n0+0]];
            v.y = frow[ids[n0+1]];
            v.z = frow[ids[n0+2]];
            v.w = frow[ids[n0+3]];
            *(float4*)&Xs[(3 + lane) * XP + n0] = v;
        }
    }
    __syncthreads();

    float acc[32];
    // ---- layer 1: 67 -> 64 ----
    {
        float bias = b1[lane];
        #pragma unroll
        for (int n = 0; n < 32; n++) acc[n] = bias;
        for (int k = 0; k < 67; k++) {
            float w = w1t[k*64 + lane];
            const float4* xr = (const float4*)&Xs[k * XP];
            #pragma unroll
            for (int n4 = 0; n4 < 8; n4++) {
                float4 xv = xr[n4];
                acc[n4*4+0] = fmaf(w, xv.x, acc[n4*4+0]);
                acc[n4*4+1] = fmaf(w, xv.y, acc[n4*4+1]);
                acc[n4*4+2] = fmaf(w, xv.z, acc[n4*4+2]);
                acc[n4*4+3] = fmaf(w, xv.w, acc[n4*4+3]);
            }
        }
        #pragma unroll
        for (int n0 = 0; n0 < 32; n0 += 4) {
            float4 v;
            v.x = fmaxf(acc[n0+0], 0.f); v.y = fmaxf(acc[n0+1], 0.f);
            v.z = fmaxf(acc[n0+2], 0.f); v.w = fmaxf(acc[n0+3], 0.f);
            *(float4*)&Hs[lane * XP + n0] = v;
        }
    }
    __syncthreads();
    // ---- layer 2: 64 -> 64 (output into Xs rows 0..63) ----
    {
        float bias = b2[lane];
        #pragma unroll
        for (int n = 0; n < 32; n++) acc[n] = bias;
        for (int k = 0; k < 64; k++) {
            float w = w2t[k*64 + lane];
            const float4* xr = (const float4*)&Hs[k * XP];
            #pragma unroll
            for (int n4 = 0; n4 < 8; n4++) {
                float4 xv = xr[n4];
                acc[n4*4+0] = fmaf(w, xv.x, acc[n4*4+0]);
                acc[n4*4+1] = fmaf(w, xv.y, acc[n4*4+1]);
                acc[n4*4+2] = fmaf(w, xv.z, acc[n4*4+2]);
                acc[n4*4+3] = fmaf(w, xv.w, acc[n4*4+3]);
            }
        }
        __syncthreads();
        #pragma unroll
        for (int n0 = 0; n0 < 32; n0 += 4) {
            float4 v;
            v.x = fmaxf(acc[n0+0], 0.f); v.y = fmaxf(acc[n0+1], 0.f);
            v.z = fmaxf(acc[n0+2], 0.f); v.w = fmaxf(acc[n0+3], 0.f);
            *(float4*)&Xs[lane * XP + n0] = v;
        }
    }
    __syncthreads();
    // ---- layer 3: 64 -> 128 (2 ch/lane) + max-pool + relu ----
    {
        float accA[32], accB[32];
        float ba = b3[lane], bb = b3[lane + 64];
        #pragma unroll
        for (int n = 0; n < 32; n++) { accA[n] = ba; accB[n] = bb; }
        for (int k = 0; k < 64; k++) {
            float wa = w3t[k*128 + lane];
            float wb = w3t[k*128 + lane + 64];
            const float4* xr = (const float4*)&Xs[k * XP];
            #pragma unroll
            for (int n4 = 0; n4 < 8; n4++) {
                float4 xv = xr[n4];
                accA[n4*4+0] = fmaf(wa, xv.x, accA[n4*4+0]);
                accA[n4*4+1] = fmaf(wa, xv.y, accA[n4*4+1]);
                accA[n4*4+2] = fmaf(wa, xv.z, accA[n4*4+2]);
                accA[n4*4+3] = fmaf(wa, xv.w, accA[n4*4+3]);
                accB[n4*4+0] = fmaf(wb, xv.x, accB[n4*4+0]);
                accB[n4*4+1] = fmaf(wb, xv.y, accB[n4*4+1]);
                accB[n4*4+2] = fmaf(wb, xv.z, accB[n4*4+2]);
                accB[n4*4+3] = fmaf(wb, xv.w, accB[n4*4+3]);
            }
        }
        float mA = accA[0], mB = accB[0];
        #pragma unroll
        for (int n = 1; n < 32; n++) { mA = fmaxf(mA, accA[n]); mB = fmaxf(mB, accB[n]); }
        mA = fmaxf(mA, 0.f); mB = fmaxf(mB, 0.f);
        out_feat[((size_t)b*128 + lane)      * NP + s] = mA;
        out_feat[((size_t)b*128 + lane + 64) * NP + s] = mB;
    }
}

// ---------------------------------------------------------------------------
extern "C" void kernel_launch(void* const* d_in, const int* in_sizes, int n_in,
                              void* d_out, int out_size, void* d_ws, size_t ws_size,
                              hipStream_t stream)
{
    const float* xyz      = (const float*)d_in[0];
    const float* features = (const float*)d_in[1];
    const float* w1 = (const float*)d_in[2];
    const float* b1 = (const float*)d_in[3];
    const float* w2 = (const float*)d_in[4];
    const float* b2 = (const float*)d_in[5];
    const float* w3 = (const float*)d_in[6];
    const float* b3 = (const float*)d_in[7];

    float* out        = (float*)d_out;
    float* out_newxyz = out;                  // (8,2048,3) = 49152 floats
    float* out_feat   = out + NB * NP * 3;    // (8,128,2048)

    char* ws = (char*)d_ws;
    int*   fps_idx = (int*)(ws + 0);          // 16384 i32  -> 65536 B
    float* w1t     = (float*)(ws + 65536);    //  4288 f32
    float* w2t     = (float*)(ws + 82688);    //  4096 f32
    float* w3t     = (float*)(ws + 99072);    //  8192 f32

    prep_kernel<<<65, 256, 0, stream>>>(w1, w2, w3, w1t, w2t, w3t);
    fps_kernel<<<NB, 256, 0, stream>>>(xyz, fps_idx, out_newxyz);
    fused_kernel<<<NB * NP, 64, 0, stream>>>(xyz, features, fps_idx,
                                             w1t, b1, w2t, b2, w3t, b3, out_feat);
}

// Round 19
// 2112.928 us; speedup vs baseline: 1.3318x; 1.3318x over previous
//
#include <hip/hip_runtime.h>
#include <stdint.h>

#define NB 8
#define NN 8192
#define NP 2048
#define NSAMP 32
#define NC 64

typedef float v2f __attribute__((ext_vector_type(2)));

// ---------------------------------------------------------------------------
// prep: weight transposes for coalesced per-k reads in the fused MLP kernel.
// ---------------------------------------------------------------------------
__global__ __launch_bounds__(256) void prep_kernel(
    const float* __restrict__ w1, const float* __restrict__ w2,
    const float* __restrict__ w3, float* __restrict__ w1t,
    float* __restrict__ w2t, float* __restrict__ w3t)
{
    int j = blockIdx.x * 256 + threadIdx.x;
    if (j < 64*67) { int o = j / 67, k = j % 67; w1t[k*64 + o] = w1[j]; }
    int j2 = j - 64*67;
    if (j2 >= 0 && j2 < 64*64) { int o = j2 >> 6, k = j2 & 63; w2t[k*64 + o] = w2[j2]; }
    int j3 = j2 - 64*64;
    if (j3 >= 0 && j3 < 128*64) { int o = j3 >> 6, k = j3 & 63; w3t[k*128 + o] = w3[j3]; }
}

// ---------------------------------------------------------------------------
// FPS v10 (r17 CHAMPION, 1705us fps / 2115us total, absmax 0.0) — restored
// byte-for-byte after r18's LDS-SoA falsification (VGPR stayed 132; added
// LDS latency on the 1-wave/SIMD critical path => 2404us).
//   - 256 threads, 1 wave/SIMD, 32 pts/lane packed v2f in registers
//   - 4 integrated strict-> chains over ascending 8-pt sub-ranges
//   - DPP wave max; ballot+ctz+readlane first-occurrence
//   - parity-dbuf 4-slot merge; ONE barrier/iter; t0 global writes
// Distance math bit-identical to r7-r18: separate-op f32, contract(off),
// per packed component: d = ((dx*dx + dy*dy) + dz*dz); dist = min(dist,d).
// Measured floor of 10 structural variants (r8-r18); remaining cost is
// 2048 serially-dependent iterations on 8 CUs (algorithmic serialization).
// ---------------------------------------------------------------------------
#define DPP_MAXF(m, CTRL) do { \
    int _s = __builtin_amdgcn_update_dpp(__float_as_int(m), __float_as_int(m), \
                                         CTRL, 0xf, 0xf, false); \
    float _f = __int_as_float(_s); \
    m = fmaxf(m, _f); } while (0)

__global__ __launch_bounds__(256, 1) void fps_kernel(
    const float* __restrict__ xyz, int* __restrict__ fps_idx,
    float* __restrict__ out_newxyz)
{
#pragma clang fp contract(off)
    __shared__ float sxyz[NN * 3];     // raw copy, 96 KiB
    __shared__ float bv[2][4];
    __shared__ int   bix[2][4];

    const int b = blockIdx.x;
    const int t = threadIdx.x;
    const int lane = t & 63;
    const int w = t >> 6;
    const float* base = xyz + (size_t)b * NN * 3;

    // stage full cloud into LDS (coalesced float4)
    for (int i = t; i < NN * 3 / 4; i += 256)
        ((float4*)sxyz)[i] = ((const float4*)base)[i];
    __syncthreads();

    // own 32 contiguous points -> packed registers (16 x v2f per coord)
    const int p0 = t * 32;
    v2f X[16], Y[16], Z[16], D[16];
    #pragma unroll
    for (int j = 0; j < 16; j++) {
        int pa = p0 + 2*j, pb = p0 + 2*j + 1;
        X[j] = (v2f){ sxyz[pa*3+0], sxyz[pb*3+0] };
        Y[j] = (v2f){ sxyz[pa*3+1], sxyz[pb*3+1] };
        Z[j] = (v2f){ sxyz[pa*3+2], sxyz[pb*3+2] };
        D[j] = (v2f){ 1e10f, 1e10f };
    }

    int far = 0;
    for (int k = 0; k < NP; k++) {
        float fx = sxyz[far * 3 + 0];
        float fy = sxyz[far * 3 + 1];
        float fz = sxyz[far * 3 + 2];
        if (t == 0) {
            fps_idx[b * NP + k] = far;
            out_newxyz[((size_t)b * NP + k) * 3 + 0] = fx;
            out_newxyz[((size_t)b * NP + k) * 3 + 1] = fy;
            out_newxyz[((size_t)b * NP + k) * 3 + 2] = fz;
        }

        v2f fx2 = { fx, fx }, fy2 = { fy, fy }, fz2 = { fz, fz };

        // 4 independent (best,idx) chains over ascending 8-point sub-ranges;
        // packed distance update, scalar strict-> bookkeeping
        float bv0 = -1.f, bv1 = -1.f, bv2 = -1.f, bv3 = -1.f;
        int   bi0 = 0,    bi1 = 0,    bi2 = 0,    bi3 = 0;
        #pragma unroll
        for (int p = 0; p < 4; p++) {
            v2f dx = X[p] - fx2, dy = Y[p] - fy2, dz = Z[p] - fz2;
            v2f d  = (dx*dx + dy*dy) + dz*dz;    // contract(off)
            v2f nd = __builtin_elementwise_min(D[p], d);
            D[p] = nd;
            if (nd.x > bv0) { bv0 = nd.x; bi0 = p0 + 2*p; }
            if (nd.y > bv0) { bv0 = nd.y; bi0 = p0 + 2*p + 1; }
        }
        #pragma unroll
        for (int p = 4; p < 8; p++) {
            v2f dx = X[p] - fx2, dy = Y[p] - fy2, dz = Z[p] - fz2;
            v2f d  = (dx*dx + dy*dy) + dz*dz;
            v2f nd = __builtin_elementwise_min(D[p], d);
            D[p] = nd;
            if (nd.x > bv1) { bv1 = nd.x; bi1 = p0 + 2*p; }
            if (nd.y > bv1) { bv1 = nd.y; bi1 = p0 + 2*p + 1; }
        }
        #pragma unroll
        for (int p = 8; p < 12; p++) {
            v2f dx = X[p] - fx2, dy = Y[p] - fy2, dz = Z[p] - fz2;
            v2f d  = (dx*dx + dy*dy) + dz*dz;
            v2f nd = __builtin_elementwise_min(D[p], d);
            D[p] = nd;
            if (nd.x > bv2) { bv2 = nd.x; bi2 = p0 + 2*p; }
            if (nd.y > bv2) { bv2 = nd.y; bi2 = p0 + 2*p + 1; }
        }
        #pragma unroll
        for (int p = 12; p < 16; p++) {
            v2f dx = X[p] - fx2, dy = Y[p] - fy2, dz = Z[p] - fz2;
            v2f d  = (dx*dx + dy*dy) + dz*dz;
            v2f nd = __builtin_elementwise_min(D[p], d);
            D[p] = nd;
            if (nd.x > bv3) { bv3 = nd.x; bi3 = p0 + 2*p; }
            if (nd.y > bv3) { bv3 = nd.y; bi3 = p0 + 2*p + 1; }
        }
        // merge chains (ranges ascend; strict > keeps earliest on tie)
        float best = bv0; int bj = bi0;
        if (bv1 > best) { best = bv1; bj = bi1; }
        if (bv2 > best) { best = bv2; bj = bi2; }
        if (bv3 > best) { best = bv3; bj = bi3; }

        // wave max via DPP (row_shr 1,2,4,8 then row_bcast 15,31 -> lane 63)
        float m = best;
        DPP_MAXF(m, 0x111); DPP_MAXF(m, 0x112); DPP_MAXF(m, 0x114);
        DPP_MAXF(m, 0x118); DPP_MAXF(m, 0x142); DPP_MAXF(m, 0x143);
        float wm = __int_as_float(__builtin_amdgcn_readlane(__float_as_int(m), 63));

        // first-occurrence: lowest lane whose best == wm (lane ranges ascend;
        // its bj is its own first occurrence)
        unsigned long long mk = __ballot(best == wm);
        int L = (int)__builtin_ctzll(mk);
        int widx = __builtin_amdgcn_readlane(bj, L);

        if (lane == 0) { bv[k & 1][w] = wm; bix[k & 1][w] = widx; }
        __syncthreads();

        // redundant 4-way merge on every wave (wave ranges ascend; strict >)
        float v0 = bv[k & 1][0], v1 = bv[k & 1][1];
        float v2 = bv[k & 1][2], v3 = bv[k & 1][3];
        int   i0 = bix[k & 1][0], i1 = bix[k & 1][1];
        int   i2 = bix[k & 1][2], i3 = bix[k & 1][3];
        float gv = v0; int gi = i0;
        if (v1 > gv) { gv = v1; gi = i1; }
        if (v2 > gv) { gv = v2; gi = i2; }
        if (v3 > gv) { gv = v3; gi = i3; }
        far = gi;
    }
}

// ---------------------------------------------------------------------------
// Fused ball-query + group + 3-layer MLP + max-pool. One wave per query.
// VERIFIED rounds 7-18 (absmax 0.0). d2: pp/qq separate-op, dot FMA chain,
// d2 separate-op, strict < 0.04f. DO NOT TOUCH.
// ---------------------------------------------------------------------------
__global__ __launch_bounds__(64) void fused_kernel(
    const float* __restrict__ xyz, const float* __restrict__ features,
    const int* __restrict__ fps_idx,
    const float* __restrict__ w1t, const float* __restrict__ b1,
    const float* __restrict__ w2t, const float* __restrict__ b2,
    const float* __restrict__ w3t, const float* __restrict__ b3,
    float* __restrict__ out_feat)
{
#pragma clang fp contract(off)
    constexpr int XP = 36;
    __shared__ __align__(16) float Xs[67 * XP];
    __shared__ __align__(16) float Hs[64 * XP];
    __shared__ int ids[NSAMP];

    const int q = blockIdx.x;           // b*NP + s
    const int b = q >> 11, s = q & (NP - 1);
    const int lane = threadIdx.x;
    const float* base = xyz + (size_t)b * NN * 3;

    // ---- ball query (one wave) ----
    int qi = fps_idx[q];
    float qx = base[qi*3+0], qy = base[qi*3+1], qz = base[qi*3+2];
    float qq = (qx*qx + qy*qy) + qz*qz;              // separate-op (contract off)
    const float RR = 0.04f;                          // f32(0.2*0.2), strict <

    int have = 0, first = 0;
    for (int c = 0; c < NN / 64; c++) {
        int p = c * 64 + lane;
        float px = base[p*3+0], py = base[p*3+1], pz = base[p*3+2];
        float pp  = (px*px + py*py) + pz*pz;         // separate-op
        float dot = fmaf(qz, pz, fmaf(qy, py, qx*px));  // einsum FMA chain
        float d2  = (qq + pp) - 2.0f*dot;            // separate-op
        bool pred = d2 < RR;
        unsigned long long m = __ballot(pred);
        if (have == 0 && m) first = c * 64 + (int)__builtin_ctzll(m);
        if (pred) {
            int rank = have + (int)__popcll(m & ((1ULL << lane) - 1ULL));
            if (rank < NSAMP) ids[rank] = p;
        }
        have += (int)__popcll(m);
        if (have >= NSAMP) break;
    }
    if (lane < NSAMP && lane >= have) ids[lane] = first;
    __syncthreads();

    // ---- build X: rows 0..2 = grouped_xyz - center, rows 3..66 = features ----
    if (lane < NSAMP) {
        int id = ids[lane];
        Xs[0*XP + lane] = base[id*3+0] - qx;
        Xs[1*XP + lane] = base[id*3+1] - qy;
        Xs[2*XP + lane] = base[id*3+2] - qz;
    }
    {
        const float* frow = features + ((size_t)b * NC + lane) * NN;
        #pragma unroll
        for (int n0 = 0; n0 < NSAMP; n0 += 4) {
            float4 v;
            v.x = frow[ids[n0+0]];
            v.y = frow[ids[n0+1]];
            v.z = frow[ids[n0+2]];
            v.w = frow[ids[n0+3]];
            *(float4*)&Xs[(3 + lane) * XP + n0] = v;
        }
    }
    __syncthreads();

    float acc[32];
    // ---- layer 1: 67 -> 64 ----
    {
        float bias = b1[lane];
        #pragma unroll
        for (int n = 0; n < 32; n++) acc[n] = bias;
        for (int k = 0; k < 67; k++) {
            float w = w1t[k*64 + lane];
            const float4* xr = (const float4*)&Xs[k * XP];
            #pragma unroll
            for (int n4 = 0; n4 < 8; n4++) {
                float4 xv = xr[n4];
                acc[n4*4+0] = fmaf(w, xv.x, acc[n4*4+0]);
                acc[n4*4+1] = fmaf(w, xv.y, acc[n4*4+1]);
                acc[n4*4+2] = fmaf(w, xv.z, acc[n4*4+2]);
                acc[n4*4+3] = fmaf(w, xv.w, acc[n4*4+3]);
            }
        }
        #pragma unroll
        for (int n0 = 0; n0 < 32; n0 += 4) {
            float4 v;
            v.x = fmaxf(acc[n0+0], 0.f); v.y = fmaxf(acc[n0+1], 0.f);
            v.z = fmaxf(acc[n0+2], 0.f); v.w = fmaxf(acc[n0+3], 0.f);
            *(float4*)&Hs[lane * XP + n0] = v;
        }
    }
    __syncthreads();
    // ---- layer 2: 64 -> 64 (output into Xs rows 0..63) ----
    {
        float bias = b2[lane];
        #pragma unroll
        for (int n = 0; n < 32; n++) acc[n] = bias;
        for (int k = 0; k < 64; k++) {
            float w = w2t[k*64 + lane];
            const float4* xr = (const float4*)&Hs[k * XP];
            #pragma unroll
            for (int n4 = 0; n4 < 8; n4++) {
                float4 xv = xr[n4];
                acc[n4*4+0] = fmaf(w, xv.x, acc[n4*4+0]);
                acc[n4*4+1] = fmaf(w, xv.y, acc[n4*4+1]);
                acc[n4*4+2] = fmaf(w, xv.z, acc[n4*4+2]);
                acc[n4*4+3] = fmaf(w, xv.w, acc[n4*4+3]);
            }
        }
        __syncthreads();
        #pragma unroll
        for (int n0 = 0; n0 < 32; n0 += 4) {
            float4 v;
            v.x = fmaxf(acc[n0+0], 0.f); v.y = fmaxf(acc[n0+1], 0.f);
            v.z = fmaxf(acc[n0+2], 0.f); v.w = fmaxf(acc[n0+3], 0.f);
            *(float4*)&Xs[lane * XP + n0] = v;
        }
    }
    __syncthreads();
    // ---- layer 3: 64 -> 128 (2 ch/lane) + max-pool + relu ----
    {
        float accA[32], accB[32];
        float ba = b3[lane], bb = b3[lane + 64];
        #pragma unroll
        for (int n = 0; n < 32; n++) { accA[n] = ba; accB[n] = bb; }
        for (int k = 0; k < 64; k++) {
            float wa = w3t[k*128 + lane];
            float wb = w3t[k*128 + lane + 64];
            const float4* xr = (const float4*)&Xs[k * XP];
            #pragma unroll
            for (int n4 = 0; n4 < 8; n4++) {
                float4 xv = xr[n4];
                accA[n4*4+0] = fmaf(wa, xv.x, accA[n4*4+0]);
                accA[n4*4+1] = fmaf(wa, xv.y, accA[n4*4+1]);
                accA[n4*4+2] = fmaf(wa, xv.z, accA[n4*4+2]);
                accA[n4*4+3] = fmaf(wa, xv.w, accA[n4*4+3]);
                accB[n4*4+0] = fmaf(wb, xv.x, accB[n4*4+0]);
                accB[n4*4+1] = fmaf(wb, xv.y, accB[n4*4+1]);
                accB[n4*4+2] = fmaf(wb, xv.z, accB[n4*4+2]);
                accB[n4*4+3] = fmaf(wb, xv.w, accB[n4*4+3]);
            }
        }
        float mA = accA[0], mB = accB[0];
        #pragma unroll
        for (int n = 1; n < 32; n++) { mA = fmaxf(mA, accA[n]); mB = fmaxf(mB, accB[n]); }
        mA = fmaxf(mA, 0.f); mB = fmaxf(mB, 0.f);
        out_feat[((size_t)b*128 + lane)      * NP + s] = mA;
        out_feat[((size_t)b*128 + lane + 64) * NP + s] = mB;
    }
}

// ---------------------------------------------------------------------------
extern "C" void kernel_launch(void* const* d_in, const int* in_sizes, int n_in,
                              void* d_out, int out_size, void* d_ws, size_t ws_size,
                              hipStream_t stream)
{
    const float* xyz      = (const float*)d_in[0];
    const float* features = (const float*)d_in[1];
    const float* w1 = (const float*)d_in[2];
    const float* b1 = (const float*)d_in[3];
    const float* w2 = (const float*)d_in[4];
    const float* b2 = (const float*)d_in[5];
    const float* w3 = (const float*)d_in[6];
    const float* b3 = (const float*)d_in[7];

    float* out        = (float*)d_out;
    float* out_newxyz = out;                  // (8,2048,3) = 49152 floats
    float* out_feat   = out + NB * NP * 3;    // (8,128,2048)

    char* ws = (char*)d_ws;
    int*   fps_idx = (int*)(ws + 0);          // 16384 i32  -> 65536 B
    float* w1t     = (float*)(ws + 65536);    //  4288 f32
    float* w2t     = (float*)(ws + 82688);    //  4096 f32
    float* w3t     = (float*)(ws + 99072);    //  8192 f32

    prep_kernel<<<65, 256, 0, stream>>>(w1, w2, w3, w1t, w2t, w3t);
    fps_kernel<<<NB, 256, 0, stream>>>(xyz, fps_idx, out_newxyz);
    fused_kernel<<<NB * NP, 64, 0, stream>>>(xyz, features, fps_idx,
                                             w1t, b1, w2t, b2, w3t, b3, out_feat);
}